// Round 1
// baseline (629.559 us; speedup 1.0000x reference)
//
#include <hip/hip_runtime.h>
#include <hip/hip_bf16.h>
#include <stdint.h>

// Transformer block for MI355X (gfx950).
// B=2 S=2048 D=1024 H=16 HD=64 E=8 K=2 HM=HS=1024, fp32 in/out, bf16 MFMA compute.

typedef __hip_bfloat16 bf16;
typedef __attribute__((ext_vector_type(8))) __bf16 bf16x8;
typedef __attribute__((ext_vector_type(4))) float f32x4;

#define S_  2048
#define D_  1024
#define N_  4096      // B*S
#define HM_ 1024
#define HS_ 1024

__device__ __forceinline__ float b2f(bf16 h) { return __bfloat162float(h); }
__device__ __forceinline__ bf16  f2b(float f) { return __float2bfloat16(f); }

__device__ __forceinline__ bf16x8 ld_bf16x8(const bf16* p) {
    union { uint4 u; bf16x8 v; } x;
    x.u = *(const uint4*)p;
    return x.v;
}

__device__ __forceinline__ void gload_lds16(const void* gsrc, void* ldst) {
    __builtin_amdgcn_global_load_lds(
        (__attribute__((address_space(1))) void*)const_cast<void*>(gsrc),
        (__attribute__((address_space(3))) void*)ldst, 16, 0, 0);
}

// ---------------------------------------------------------------------------
// fp32 -> bf16 transpose-convert: out[(c*rowmul+rowoff)*ld_out + r] = in[r*ld_in + c]
// grid: (C/32, R/32, batch), block 256
// ---------------------------------------------------------------------------
__global__ __launch_bounds__(256)
void transpose_cvt(const float* __restrict__ in, bf16* __restrict__ out,
                   int ld_in, int ld_out, int rowmul, int rowoff,
                   long in_bstride, long out_bstride)
{
    __shared__ float t[32][33];
    const int e = blockIdx.z;
    in  += (size_t)e * in_bstride;
    out += (size_t)e * out_bstride;
    const int c0 = blockIdx.x * 32, r0 = blockIdx.y * 32;
    const int tx = threadIdx.x & 31, ty = threadIdx.x >> 5;   // ty 0..7
#pragma unroll
    for (int i = 0; i < 32; i += 8)
        t[ty + i][tx] = in[(size_t)(r0 + ty + i) * ld_in + c0 + tx];
    __syncthreads();
#pragma unroll
    for (int i = 0; i < 32; i += 8)
        out[(size_t)((c0 + ty + i) * rowmul + rowoff) * ld_out + r0 + tx] = f2b(t[tx][ty + i]);
}

// ---------------------------------------------------------------------------
// RMSNorm: fp32 in -> bf16 out.  grid N_, block 256 (4 f32 per thread, D=1024)
// ---------------------------------------------------------------------------
__global__ __launch_bounds__(256)
void rmsnorm_kernel(const float* __restrict__ x, const float* __restrict__ w,
                    bf16* __restrict__ out)
{
    const int n = blockIdx.x;
    const int tid = threadIdx.x;
    const float4 v = *(const float4*)(x + (size_t)n * D_ + tid * 4);
    float ss = v.x * v.x + v.y * v.y + v.z * v.z + v.w * v.w;
#pragma unroll
    for (int m = 1; m < 64; m <<= 1) ss += __shfl_xor(ss, m);
    __shared__ float red[4];
    if ((tid & 63) == 0) red[tid >> 6] = ss;
    __syncthreads();
    const float tot = red[0] + red[1] + red[2] + red[3];
    const float rstd = rsqrtf(tot * (1.0f / D_) + 1e-6f);
    const float4 wv = *(const float4*)(w + tid * 4);
    union { bf16 h[4]; uint2 u; } pk;
    pk.h[0] = f2b(v.x * rstd * wv.x);
    pk.h[1] = f2b(v.y * rstd * wv.y);
    pk.h[2] = f2b(v.z * rstd * wv.z);
    pk.h[3] = f2b(v.w * rstd * wv.w);
    *(uint2*)(out + (size_t)n * D_ + tid * 4) = pk.u;
}

// ---------------------------------------------------------------------------
// GEMM: C[M][N] = A[M][K] * Bt[N][K]^T  (A,Bt bf16 row-major; acc fp32)
// 128x128 tile, BK=32, 256 threads (4 waves, 2x2), mfma 16x16x32 bf16.
// EPI: 0 = store bf16, 1 = store fp32, 2 = fp32 resid add, 3 = swiglu pair -> bf16
// MODE: 0 = plain, 1 = grouped+gathered A rows (token_list), 2 = grouped contiguous
// ---------------------------------------------------------------------------
template<int EPI, int MODE>
__global__ __launch_bounds__(256)
void gemm_bt(const bf16* __restrict__ A, const bf16* __restrict__ Bt,
             void* __restrict__ Cout, const float* __restrict__ resid,
             int M, int Kdim, int lda, int ldb, int ldc, long bstride,
             const int* __restrict__ tlist, const int* __restrict__ offs,
             const int* __restrict__ cnt)
{
    __shared__ bf16 As[128 * 32];
    __shared__ bf16 Bs[128 * 32];
    const int tid = threadIdx.x;
    const int wave = tid >> 6, lane = tid & 63;

    int mcount = M, outBase = 0;
    const bf16* Bp = Bt;
    if (MODE != 0) {
        const int e = blockIdx.z;
        mcount = cnt[e];
        Bp = Bt + (size_t)e * bstride;
        outBase = offs[e];
    }
    const int m0 = blockIdx.y * 128;
    if (m0 >= mcount) return;
    const int n0 = blockIdx.x * 128;

    // staging mapping: thread -> (row, k-chunk); LDS linear [128][32]
    const int srow = tid >> 2;
    const int scol = (tid & 3) * 8;
    const bf16* aptr[2];
    const bf16* bptr[2];
#pragma unroll
    for (int i = 0; i < 2; i++) {
        int r = m0 + i * 64 + srow;
        if (r >= mcount) r = mcount - 1;
        long arow;
        if (MODE == 1)      arow = tlist[outBase + r];
        else if (MODE == 2) arow = (long)outBase + r;
        else                arow = r;
        aptr[i] = A + (size_t)arow * lda + scol;
        bptr[i] = Bp + (size_t)(n0 + i * 64 + srow) * ldb + scol;
    }

    f32x4 zero4 = {0.f, 0.f, 0.f, 0.f};
    f32x4 acc[4][4];
#pragma unroll
    for (int m = 0; m < 4; m++)
#pragma unroll
        for (int n = 0; n < 4; n++) acc[m][n] = zero4;

    const int wm = (wave >> 1) * 64, wn = (wave & 1) * 64;
    const int fr = lane & 15, fk = (lane >> 4) * 8;
    const int aoff = (wm + fr) * 32 + fk;
    const int boff = (wn + fr) * 32 + fk;

    for (int kt = 0; kt < Kdim; kt += 32) {
        __syncthreads();
#pragma unroll
        for (int i = 0; i < 2; i++) {
            gload_lds16(aptr[i] + kt, (char*)As + i * 4096 + wave * 1024);
            gload_lds16(bptr[i] + kt, (char*)Bs + i * 4096 + wave * 1024);
        }
        __syncthreads();
        bf16x8 af[4], bfr[4];
#pragma unroll
        for (int m = 0; m < 4; m++) af[m] = ld_bf16x8(&As[aoff + m * 512]);
#pragma unroll
        for (int n = 0; n < 4; n++) bfr[n] = ld_bf16x8(&Bs[boff + n * 512]);
#pragma unroll
        for (int m = 0; m < 4; m++)
#pragma unroll
            for (int n = 0; n < 4; n++)
                acc[m][n] = __builtin_amdgcn_mfma_f32_16x16x32_bf16(af[m], bfr[n], acc[m][n], 0, 0, 0);
    }

    const int crow = m0 + wm + (lane >> 4) * 4;
    const int ccol = n0 + wn + fr;
#pragma unroll
    for (int m = 0; m < 4; m++)
#pragma unroll
        for (int n = 0; n < 4; n++)
#pragma unroll
            for (int j = 0; j < 4; j++) {
                const int r = crow + m * 16 + j;
                const int c = ccol + n * 16;
                const float v = acc[m][n][j];
                if (EPI == 3) {
                    const float other = __shfl_xor(v, 1);
                    const float res = (v / (1.f + __expf(-v))) * other;  // silu(g1)*g3 on even lanes
                    if (((lane & 1) == 0) && r < mcount)
                        ((bf16*)Cout)[(size_t)(outBase + r) * ldc + (c >> 1)] = f2b(res);
                } else if (r < mcount) {
                    const size_t oi = (size_t)(outBase + r) * ldc + c;
                    if (EPI == 0)      ((bf16*)Cout)[oi] = f2b(v);
                    else if (EPI == 1) ((float*)Cout)[oi] = v;
                    else               ((float*)Cout)[oi] = resid[oi] + v;
                }
            }
}

// ---------------------------------------------------------------------------
// RoPE in-place on q,k sections of qkv [N][3072]; q additionally scaled 1/8.
// ---------------------------------------------------------------------------
__global__ __launch_bounds__(256)
void rope_kernel(bf16* __restrict__ qkv, const float* __restrict__ fc, const float* __restrict__ fs)
{
    const int n = blockIdx.x;
    const int s = n & (S_ - 1);
    bf16* row = qkv + (size_t)n * 3072;
    for (int p = threadIdx.x; p < 1024; p += 256) {
        const int sec = p >> 9;           // 0=q, 1=k
        const int idx = p & 511;
        const int hh = idx >> 5, j = idx & 31;
        const int col = sec * 1024 + hh * 64 + 2 * j;
        const float c = fc[s * 32 + j], si = fs[s * 32 + j];
        const float v0 = b2f(row[col]), v1 = b2f(row[col + 1]);
        float o0 = v0 * c - v1 * si;
        float o1 = v0 * si + v1 * c;
        if (sec == 0) { o0 *= 0.125f; o1 *= 0.125f; }   // fold 1/sqrt(HD) into q
        row[col] = f2b(o0);
        row[col + 1] = f2b(o1);
    }
}

// ---------------------------------------------------------------------------
// Flash attention, non-causal. grid (S/128, H=16, B=2), block 256 (4 waves).
// Each wave: 32 q-rows. KV tile = 64. qkv rows stride 3072 (q|k|v sections).
// out: bf16 [N][1024] at col h*64+hd.
// ---------------------------------------------------------------------------
__global__ __launch_bounds__(256)
void attn_kernel(const bf16* __restrict__ qkv, bf16* __restrict__ out)
{
    __shared__ bf16 Ks[64 * 72];
    __shared__ bf16 Vts[64 * 72];
    __shared__ bf16 Pw[4][32 * 72];
    const int tid = threadIdx.x, wave = tid >> 6, lane = tid & 63;
    const int b = blockIdx.z, hh = blockIdx.y;
    const int q0 = blockIdx.x * 128;
    const bf16* base  = qkv + ((size_t)b * S_) * 3072 + hh * 64;
    const bf16* kbase = base + 1024;
    const bf16* vbase = base + 2048;
    const int fr = lane & 15, fg = lane >> 4;

    bf16x8 aq[2][2];
#pragma unroll
    for (int qb = 0; qb < 2; qb++)
#pragma unroll
        for (int s2 = 0; s2 < 2; s2++) {
            const int qr = q0 + wave * 32 + qb * 16 + fr;
            aq[qb][s2] = ld_bf16x8(base + (size_t)qr * 3072 + s2 * 32 + fg * 8);
        }

    f32x4 zero4 = {0.f, 0.f, 0.f, 0.f};
    f32x4 acc_o[2][4];
    float mrow[2][4], lrow[2][4];
#pragma unroll
    for (int qb = 0; qb < 2; qb++) {
#pragma unroll
        for (int hf = 0; hf < 4; hf++) acc_o[qb][hf] = zero4;
#pragma unroll
        for (int j = 0; j < 4; j++) { mrow[qb][j] = -1e30f; lrow[qb][j] = 0.f; }
    }

    const int srow = tid >> 2;
    const int scol = (tid & 3) * 16;

    for (int kv0 = 0; kv0 < S_; kv0 += 64) {
        __syncthreads();
        {
            const bf16* kr = kbase + (size_t)(kv0 + srow) * 3072 + scol;
            *(uint4*)&Ks[srow * 72 + scol]     = *(const uint4*)kr;
            *(uint4*)&Ks[srow * 72 + scol + 8] = *(const uint4*)(kr + 8);
            const bf16* vr = vbase + (size_t)(kv0 + srow) * 3072 + scol;
            union { uint4 u[2]; bf16 h[16]; } vt;
            vt.u[0] = *(const uint4*)vr;
            vt.u[1] = *(const uint4*)(vr + 8);
#pragma unroll
            for (int t2 = 0; t2 < 16; t2++)
                Vts[(scol + t2) * 72 + srow] = vt.h[t2];
        }
        __syncthreads();

        f32x4 sc[2][4];
#pragma unroll
        for (int qb = 0; qb < 2; qb++)
#pragma unroll
            for (int f = 0; f < 4; f++) sc[qb][f] = zero4;

#pragma unroll
        for (int f = 0; f < 4; f++) {
            const bf16x8 bk0 = ld_bf16x8(&Ks[(f * 16 + fr) * 72 + fg * 8]);
            const bf16x8 bk1 = ld_bf16x8(&Ks[(f * 16 + fr) * 72 + 32 + fg * 8]);
#pragma unroll
            for (int qb = 0; qb < 2; qb++) {
                sc[qb][f] = __builtin_amdgcn_mfma_f32_16x16x32_bf16(aq[qb][0], bk0, sc[qb][f], 0, 0, 0);
                sc[qb][f] = __builtin_amdgcn_mfma_f32_16x16x32_bf16(aq[qb][1], bk1, sc[qb][f], 0, 0, 0);
            }
        }

#pragma unroll
        for (int qb = 0; qb < 2; qb++) {
            float mnew[4], scal[4], psum[4];
#pragma unroll
            for (int j = 0; j < 4; j++) {
                float pm = fmaxf(fmaxf(sc[qb][0][j], sc[qb][1][j]), fmaxf(sc[qb][2][j], sc[qb][3][j]));
#pragma unroll
                for (int msk = 1; msk < 16; msk <<= 1)
                    pm = fmaxf(pm, __shfl_xor(pm, msk));
                mnew[j] = fmaxf(mrow[qb][j], pm);
                scal[j] = __expf(mrow[qb][j] - mnew[j]);
                mrow[qb][j] = mnew[j];
                psum[j] = 0.f;
            }
#pragma unroll
            for (int f = 0; f < 4; f++)
#pragma unroll
                for (int j = 0; j < 4; j++) {
                    const float p = __expf(sc[qb][f][j] - mnew[j]);
                    sc[qb][f][j] = p;
                    psum[j] += p;
                }
#pragma unroll
            for (int j = 0; j < 4; j++) {
                float ps = psum[j];
#pragma unroll
                for (int msk = 1; msk < 16; msk <<= 1)
                    ps += __shfl_xor(ps, msk);
                lrow[qb][j] = lrow[qb][j] * scal[j] + ps;
            }
#pragma unroll
            for (int hf = 0; hf < 4; hf++)
#pragma unroll
                for (int j = 0; j < 4; j++)
                    acc_o[qb][hf][j] *= scal[j];
#pragma unroll
            for (int f = 0; f < 4; f++)
#pragma unroll
                for (int j = 0; j < 4; j++)
                    Pw[wave][(qb * 16 + fg * 4 + j) * 72 + f * 16 + fr] = f2b(sc[qb][f][j]);
        }

#pragma unroll
        for (int qb = 0; qb < 2; qb++) {
#pragma unroll
            for (int s2 = 0; s2 < 2; s2++) {
                const bf16x8 ap = ld_bf16x8(&Pw[wave][(qb * 16 + fr) * 72 + s2 * 32 + fg * 8]);
#pragma unroll
                for (int hf = 0; hf < 4; hf++) {
                    const bf16x8 bv = ld_bf16x8(&Vts[(hf * 16 + fr) * 72 + s2 * 32 + fg * 8]);
                    acc_o[qb][hf] = __builtin_amdgcn_mfma_f32_16x16x32_bf16(ap, bv, acc_o[qb][hf], 0, 0, 0);
                }
            }
        }
    }

#pragma unroll
    for (int qb = 0; qb < 2; qb++) {
        float inv[4];
#pragma unroll
        for (int j = 0; j < 4; j++) inv[j] = 1.f / lrow[qb][j];
#pragma unroll
        for (int hf = 0; hf < 4; hf++)
#pragma unroll
            for (int j = 0; j < 4; j++) {
                const int r = q0 + wave * 32 + qb * 16 + fg * 4 + j;
                out[((size_t)(b * S_ + r)) * D_ + hh * 64 + hf * 16 + fr] =
                    f2b(acc_o[qb][hf][j] * inv[j]);
            }
    }
}

// ---------------------------------------------------------------------------
// MoE gating: fp32 scores from pre-norm h (recompute rmsnorm scale), top-2.
// grid N_/4, block 256 (1 wave per token).
// ---------------------------------------------------------------------------
__global__ __launch_bounds__(256)
void gating_kernel(const float* __restrict__ h, const float* __restrict__ gw,
                   const float* __restrict__ wnorm,
                   int* __restrict__ cnt, int* __restrict__ top_idx, float* __restrict__ top_w)
{
    const int wave = threadIdx.x >> 6, lane = threadIdx.x & 63;
    const int n = blockIdx.x * 4 + wave;
    const float* hr = h + (size_t)n * D_;
    float acc[8] = {0.f, 0.f, 0.f, 0.f, 0.f, 0.f, 0.f, 0.f};
    float ss = 0.f;
    for (int d = lane * 4; d < D_; d += 256) {
        const float4 hv = *(const float4*)(hr + d);
        const float4 wv = *(const float4*)(wnorm + d);
        ss += hv.x * hv.x + hv.y * hv.y + hv.z * hv.z + hv.w * hv.w;
        const float x0 = hv.x * wv.x, x1 = hv.y * wv.y, x2 = hv.z * wv.z, x3 = hv.w * wv.w;
#pragma unroll
        for (int e2 = 0; e2 < 8; e2++) {
            const float4 gv = *(const float4*)(gw + e2 * D_ + d);
            acc[e2] += x0 * gv.x + x1 * gv.y + x2 * gv.z + x3 * gv.w;
        }
    }
#pragma unroll
    for (int m = 1; m < 64; m <<= 1) {
        ss += __shfl_xor(ss, m);
#pragma unroll
        for (int e2 = 0; e2 < 8; e2++) acc[e2] += __shfl_xor(acc[e2], m);
    }
    if (lane == 0) {
        const float rstd = rsqrtf(ss * (1.0f / D_) + 1e-6f);
        float s[8];
#pragma unroll
        for (int e2 = 0; e2 < 8; e2++) s[e2] = acc[e2] * rstd;
        int e0 = 0;
#pragma unroll
        for (int e2 = 1; e2 < 8; e2++) if (s[e2] > s[e0]) e0 = e2;
        int e1 = (e0 == 0) ? 1 : 0;
#pragma unroll
        for (int e2 = 0; e2 < 8; e2++) if (e2 != e0 && s[e2] > s[e1]) e1 = e2;
        const float mx = s[e0];
        float Z = 0.f;
        float p[8];
#pragma unroll
        for (int e2 = 0; e2 < 8; e2++) { p[e2] = __expf(s[e2] - mx); Z += p[e2]; }
        const float v0 = p[e0] / Z, v1 = p[e1] / Z;
        const float sm = v0 + v1 + 1e-9f;
        top_idx[n * 2] = e0; top_idx[n * 2 + 1] = e1;
        top_w[n * 2] = v0 / sm; top_w[n * 2 + 1] = v1 / sm;
        atomicAdd(&cnt[e0], 1);
        atomicAdd(&cnt[e1], 1);
    }
}

__global__ __launch_bounds__(64)
void scan_kernel(const int* __restrict__ cnt, int* __restrict__ offs, int* __restrict__ cnt2)
{
    if (threadIdx.x == 0) {
        int o = 0;
        for (int e = 0; e < 8; e++) { offs[e] = o; o += cnt[e]; cnt2[e] = 0; }
        offs[8] = o;
    }
}

__global__ __launch_bounds__(256)
void scatter_kernel(const int* __restrict__ top_idx, int* __restrict__ cnt2,
                    const int* __restrict__ offs, int* __restrict__ token_list,
                    int* __restrict__ tok_pos)
{
    const int n = blockIdx.x * 256 + threadIdx.x;
#pragma unroll
    for (int k = 0; k < 2; k++) {
        const int e = top_idx[n * 2 + k];
        const int pos = offs[e] + atomicAdd(&cnt2[e], 1);
        token_list[pos] = n;
        tok_pos[n * 2 + k] = pos;
    }
}

// out = h + y_shared + w0*eo[pos0] + w1*eo[pos1]
__global__ __launch_bounds__(256)
void combine_kernel(const float* __restrict__ h, const float* __restrict__ y,
                    const bf16* __restrict__ eo, const int* __restrict__ tok_pos,
                    const float* __restrict__ top_w, float* __restrict__ out)
{
    const int idx = blockIdx.x * 256 + threadIdx.x;   // N_*D_/4 total
    const int n = idx >> 8;
    const int c = (idx & 255) * 4;
    const float4 hv = *(const float4*)(h + (size_t)n * D_ + c);
    const float4 yv = *(const float4*)(y + (size_t)n * D_ + c);
    const int p0 = tok_pos[n * 2], p1 = tok_pos[n * 2 + 1];
    const float w0 = top_w[n * 2], w1 = top_w[n * 2 + 1];
    union { uint2 u; bf16 hh[4]; } a0, a1;
    a0.u = *(const uint2*)(eo + (size_t)p0 * D_ + c);
    a1.u = *(const uint2*)(eo + (size_t)p1 * D_ + c);
    float4 r;
    r.x = hv.x + yv.x + w0 * b2f(a0.hh[0]) + w1 * b2f(a1.hh[0]);
    r.y = hv.y + yv.y + w0 * b2f(a0.hh[1]) + w1 * b2f(a1.hh[1]);
    r.z = hv.z + yv.z + w0 * b2f(a0.hh[2]) + w1 * b2f(a1.hh[2]);
    r.w = hv.w + yv.w + w0 * b2f(a0.hh[3]) + w1 * b2f(a1.hh[3]);
    *(float4*)(out + (size_t)n * D_ + c) = r;
}

// ---------------------------------------------------------------------------
extern "C" void kernel_launch(void* const* d_in, const int* in_sizes, int n_in,
                              void* d_out, int out_size, void* d_ws, size_t ws_size,
                              hipStream_t stream)
{
    const float* x   = (const float*)d_in[0];
    const float* fc  = (const float*)d_in[1];
    const float* fs  = (const float*)d_in[2];
    const float* anw = (const float*)d_in[3];
    const float* fnw = (const float*)d_in[4];
    const float* wq  = (const float*)d_in[5];
    const float* wk  = (const float*)d_in[6];
    const float* wv  = (const float*)d_in[7];
    const float* wo  = (const float*)d_in[8];
    const float* gw  = (const float*)d_in[9];
    const float* ew1 = (const float*)d_in[10];
    const float* ew2 = (const float*)d_in[11];
    const float* ew3 = (const float*)d_in[12];
    const float* sw1 = (const float*)d_in[13];
    const float* sw2 = (const float*)d_in[14];
    const float* sw3 = (const float*)d_in[15];

    char* ws = (char*)d_ws;
    bf16*  wqkv_t = (bf16*)(ws + 0);           //  6291456 B  [3072][1024]
    bf16*  wo_t   = (bf16*)(ws + 6291456);     //  2097152 B  [1024][1024]
    bf16*  sw13_t = (bf16*)(ws + 8388608);     //  4194304 B  [2048][1024] interleaved
    bf16*  sw2_t  = (bf16*)(ws + 12582912);    //  2097152 B  [1024][1024]
    bf16*  ew13_t = (bf16*)(ws + 14680064);    // 33554432 B  E x [2048][1024] interleaved
    bf16*  ew2_t  = (bf16*)(ws + 48234496);    // 16777216 B  E x [1024][1024]
    bf16*  xn     = (bf16*)(ws + 65011712);    //  8388608 B  [4096][1024]  (reused as xf)
    bf16*  qkv    = (bf16*)(ws + 73400320);    // 25165824 B  [4096][3072]  (reused as h1 [8192][1024])
    bf16*  attn   = (bf16*)(ws + 98566144);    //  8388608 B  [4096][1024]  (reused as hsh)
    float* hbuf   = (float*)(ws + 106954752);  // 16777216 B  [4096][1024]
    float* ybuf   = (float*)(ws + 123731968);  // 16777216 B  [4096][1024]
    bf16*  eo     = (bf16*)(ws + 140509184);   // 16777216 B  [8192][1024]
    char*  misc   = ws + 157286400;
    int*   cnt        = (int*)(misc + 0);
    int*   cnt2       = (int*)(misc + 32);
    int*   offs       = (int*)(misc + 64);
    int*   top_idx    = (int*)(misc + 128);
    float* top_w      = (float*)(misc + 128 + 32768);
    int*   token_list = (int*)(misc + 128 + 65536);
    int*   tok_pos    = (int*)(misc + 128 + 98304);

    hipMemsetAsync(misc, 0, 128, stream);

    const dim3 tb(256);
    // weight transpose + bf16 convert (all slices are 1024x1024)
    transpose_cvt<<<dim3(32, 32, 1), tb, 0, stream>>>(wq,  wqkv_t,              1024, 1024, 1, 0, 0, 0);
    transpose_cvt<<<dim3(32, 32, 1), tb, 0, stream>>>(wk,  wqkv_t + 1024*1024,  1024, 1024, 1, 0, 0, 0);
    transpose_cvt<<<dim3(32, 32, 1), tb, 0, stream>>>(wv,  wqkv_t + 2048*1024,  1024, 1024, 1, 0, 0, 0);
    transpose_cvt<<<dim3(32, 32, 1), tb, 0, stream>>>(wo,  wo_t,                1024, 1024, 1, 0, 0, 0);
    transpose_cvt<<<dim3(32, 32, 1), tb, 0, stream>>>(sw1, sw13_t,              1024, 1024, 2, 0, 0, 0);
    transpose_cvt<<<dim3(32, 32, 1), tb, 0, stream>>>(sw3, sw13_t,              1024, 1024, 2, 1, 0, 0);
    transpose_cvt<<<dim3(32, 32, 1), tb, 0, stream>>>(sw2, sw2_t,               1024, 1024, 1, 0, 0, 0);
    transpose_cvt<<<dim3(32, 32, 8), tb, 0, stream>>>(ew1, ew13_t,              1024, 1024, 2, 0, 1048576, 2097152);
    transpose_cvt<<<dim3(32, 32, 8), tb, 0, stream>>>(ew3, ew13_t,              1024, 1024, 2, 1, 1048576, 2097152);
    transpose_cvt<<<dim3(32, 32, 8), tb, 0, stream>>>(ew2, ew2_t,               1024, 1024, 1, 0, 1048576, 1048576);

    // attention branch
    rmsnorm_kernel<<<N_, tb, 0, stream>>>(x, anw, xn);
    gemm_bt<0, 0><<<dim3(24, 32, 1), tb, 0, stream>>>(xn, wqkv_t, qkv, nullptr,
        N_, 1024, 1024, 1024, 3072, 0, nullptr, nullptr, nullptr);
    rope_kernel<<<N_, tb, 0, stream>>>(qkv, fc, fs);
    attn_kernel<<<dim3(16, 16, 2), tb, 0, stream>>>(qkv, attn);
    gemm_bt<2, 0><<<dim3(8, 32, 1), tb, 0, stream>>>(attn, wo_t, hbuf, x,
        N_, 1024, 1024, 1024, 1024, 0, nullptr, nullptr, nullptr);

    // FFN branch
    rmsnorm_kernel<<<N_, tb, 0, stream>>>(hbuf, fnw, xn);   // xn = xf now
    gating_kernel<<<N_ / 4, tb, 0, stream>>>(hbuf, gw, fnw, cnt, top_idx, top_w);
    scan_kernel<<<1, 64, 0, stream>>>(cnt, offs, cnt2);
    scatter_kernel<<<N_ / 256, tb, 0, stream>>>(top_idx, cnt2, offs, token_list, tok_pos);

    // shared expert: hsh = silu(xf@sw1)*(xf@sw3); y = hsh@sw2
    gemm_bt<3, 0><<<dim3(16, 32, 1), tb, 0, stream>>>(xn, sw13_t, attn, nullptr,
        N_, 1024, 1024, 1024, 1024, 0, nullptr, nullptr, nullptr);      // attn = hsh now
    gemm_bt<1, 0><<<dim3(8, 32, 1), tb, 0, stream>>>(attn, sw2_t, ybuf, nullptr,
        N_, 1024, 1024, 1024, 1024, 0, nullptr, nullptr, nullptr);

    // routed experts (top-2): h1 = silu(xg@ew1)*(xg@ew3); eo = h1@ew2
    gemm_bt<3, 1><<<dim3(16, 32, 8), tb, 0, stream>>>(xn, ew13_t, qkv, nullptr,
        0, 1024, 1024, 1024, 1024, 2097152, token_list, offs, cnt);     // qkv = h1 now
    gemm_bt<0, 2><<<dim3(8, 32, 8), tb, 0, stream>>>((const bf16*)qkv, ew2_t, eo, nullptr,
        0, 1024, 1024, 1024, 1024, 1048576, nullptr, offs, cnt);

    combine_kernel<<<4096, tb, 0, stream>>>(hbuf, ybuf, eo, tok_pos, top_w, (float*)d_out);
}

// Round 2
// 556.471 us; speedup vs baseline: 1.1313x; 1.1313x over previous
//
#include <hip/hip_runtime.h>
#include <hip/hip_bf16.h>
#include <stdint.h>

// Transformer block for MI355X (gfx950).
// B=2 S=2048 D=1024 H=16 HD=64 E=8 K=2 HM=HS=1024, fp32 in/out, bf16 MFMA compute.

typedef __hip_bfloat16 bf16;
typedef __attribute__((ext_vector_type(8))) __bf16 bf16x8;
typedef __attribute__((ext_vector_type(4))) float f32x4;
typedef __attribute__((ext_vector_type(2))) unsigned int u32x2;

#define S_  2048
#define D_  1024
#define N_  4096      // B*S
#define HM_ 1024
#define HS_ 1024

__device__ __forceinline__ float b2f(bf16 h) { return __bfloat162float(h); }
__device__ __forceinline__ bf16  f2b(float f) { return __float2bfloat16(f); }

__device__ __forceinline__ bf16x8 ld_bf16x8(const bf16* p) {
    union { uint4 u; bf16x8 v; } x;
    x.u = *(const uint4*)p;
    return x.v;
}

__device__ __forceinline__ void gload_lds16(const void* gsrc, void* ldst) {
    __builtin_amdgcn_global_load_lds(
        (__attribute__((address_space(1))) void*)const_cast<void*>(gsrc),
        (__attribute__((address_space(3))) void*)ldst, 16, 0, 0);
}

// gfx950 LDS transpose read: lane l gets column (l&15) of the 4x16 bf16 tile
// supplied by its 16-lane group's 128B window (per-lane addr = base + 8*lane).
__device__ __forceinline__ u32x2 tr16_read(unsigned lds_off) {
    u32x2 d;
    asm volatile("ds_read_b64_tr_b16 %0, %1" : "=v"(d) : "v"(lds_off));
    return d;
}

// ---------------------------------------------------------------------------
// fp32 -> bf16 transpose-convert: out[(c*rowmul+rowoff)*ld_out + r] = in[r*ld_in + c]
// ---------------------------------------------------------------------------
__global__ __launch_bounds__(256)
void transpose_cvt(const float* __restrict__ in, bf16* __restrict__ out,
                   int ld_in, int ld_out, int rowmul, int rowoff,
                   long in_bstride, long out_bstride)
{
    __shared__ float t[32][33];
    const int e = blockIdx.z;
    in  += (size_t)e * in_bstride;
    out += (size_t)e * out_bstride;
    const int c0 = blockIdx.x * 32, r0 = blockIdx.y * 32;
    const int tx = threadIdx.x & 31, ty = threadIdx.x >> 5;   // ty 0..7
#pragma unroll
    for (int i = 0; i < 32; i += 8)
        t[ty + i][tx] = in[(size_t)(r0 + ty + i) * ld_in + c0 + tx];
    __syncthreads();
#pragma unroll
    for (int i = 0; i < 32; i += 8)
        out[(size_t)((c0 + ty + i) * rowmul + rowoff) * ld_out + r0 + tx] = f2b(t[tx][ty + i]);
}

// ---------------------------------------------------------------------------
// RMSNorm: fp32 in -> bf16 out.  grid N_, block 256
// ---------------------------------------------------------------------------
__global__ __launch_bounds__(256)
void rmsnorm_kernel(const float* __restrict__ x, const float* __restrict__ w,
                    bf16* __restrict__ out)
{
    const int n = blockIdx.x;
    const int tid = threadIdx.x;
    const float4 v = *(const float4*)(x + (size_t)n * D_ + tid * 4);
    float ss = v.x * v.x + v.y * v.y + v.z * v.z + v.w * v.w;
#pragma unroll
    for (int m = 1; m < 64; m <<= 1) ss += __shfl_xor(ss, m);
    __shared__ float red[4];
    if ((tid & 63) == 0) red[tid >> 6] = ss;
    __syncthreads();
    const float tot = red[0] + red[1] + red[2] + red[3];
    const float rstd = rsqrtf(tot * (1.0f / D_) + 1e-6f);
    const float4 wv = *(const float4*)(w + tid * 4);
    union { bf16 h[4]; uint2 u; } pk;
    pk.h[0] = f2b(v.x * rstd * wv.x);
    pk.h[1] = f2b(v.y * rstd * wv.y);
    pk.h[2] = f2b(v.z * rstd * wv.z);
    pk.h[3] = f2b(v.w * rstd * wv.w);
    *(uint2*)(out + (size_t)n * D_ + tid * 4) = pk.u;
}

// ---------------------------------------------------------------------------
// GEMM: C[M][N] = A[M][K] * Bt[N][K]^T  (A,Bt bf16 row-major; acc fp32)
// 128x128 tile, BK=32, 256 threads (4 waves, 2x2), mfma 16x16x32 bf16.
// EPI: 0 = store bf16, 1 = store fp32, 2 = fp32 resid add, 3 = swiglu pair -> bf16
// MODE: 0 = plain, 1 = grouped+gathered A rows (token_list), 2 = grouped contiguous
// ---------------------------------------------------------------------------
template<int EPI, int MODE>
__global__ __launch_bounds__(256)
void gemm_bt(const bf16* __restrict__ A, const bf16* __restrict__ Bt,
             void* __restrict__ Cout, const float* __restrict__ resid,
             int M, int Kdim, int lda, int ldb, int ldc, long bstride,
             const int* __restrict__ tlist, const int* __restrict__ offs,
             const int* __restrict__ cnt)
{
    __shared__ bf16 As[128 * 32];
    __shared__ bf16 Bs[128 * 32];
    const int tid = threadIdx.x;
    const int wave = tid >> 6, lane = tid & 63;

    int mcount = M, outBase = 0;
    const bf16* Bp = Bt;
    if (MODE != 0) {
        const int e = blockIdx.z;
        mcount = cnt[e];
        Bp = Bt + (size_t)e * bstride;
        outBase = offs[e];
    }
    const int m0 = blockIdx.y * 128;
    if (m0 >= mcount) return;
    const int n0 = blockIdx.x * 128;

    const int srow = tid >> 2;
    const int scol = (tid & 3) * 8;
    const bf16* aptr[2];
    const bf16* bptr[2];
#pragma unroll
    for (int i = 0; i < 2; i++) {
        int r = m0 + i * 64 + srow;
        if (r >= mcount) r = mcount - 1;
        long arow;
        if (MODE == 1)      arow = tlist[outBase + r];
        else if (MODE == 2) arow = (long)outBase + r;
        else                arow = r;
        aptr[i] = A + (size_t)arow * lda + scol;
        bptr[i] = Bp + (size_t)(n0 + i * 64 + srow) * ldb + scol;
    }

    f32x4 zero4 = {0.f, 0.f, 0.f, 0.f};
    f32x4 acc[4][4];
#pragma unroll
    for (int m = 0; m < 4; m++)
#pragma unroll
        for (int n = 0; n < 4; n++) acc[m][n] = zero4;

    const int wm = (wave >> 1) * 64, wn = (wave & 1) * 64;
    const int fr = lane & 15, fk = (lane >> 4) * 8;
    const int aoff = (wm + fr) * 32 + fk;
    const int boff = (wn + fr) * 32 + fk;

    for (int kt = 0; kt < Kdim; kt += 32) {
        __syncthreads();
#pragma unroll
        for (int i = 0; i < 2; i++) {
            gload_lds16(aptr[i] + kt, (char*)As + i * 4096 + wave * 1024);
            gload_lds16(bptr[i] + kt, (char*)Bs + i * 4096 + wave * 1024);
        }
        __syncthreads();
        bf16x8 af[4], bfr[4];
#pragma unroll
        for (int m = 0; m < 4; m++) af[m] = ld_bf16x8(&As[aoff + m * 512]);
#pragma unroll
        for (int n = 0; n < 4; n++) bfr[n] = ld_bf16x8(&Bs[boff + n * 512]);
#pragma unroll
        for (int m = 0; m < 4; m++)
#pragma unroll
            for (int n = 0; n < 4; n++)
                acc[m][n] = __builtin_amdgcn_mfma_f32_16x16x32_bf16(af[m], bfr[n], acc[m][n], 0, 0, 0);
    }

    const int crow = m0 + wm + (lane >> 4) * 4;
    const int ccol = n0 + wn + fr;
#pragma unroll
    for (int m = 0; m < 4; m++)
#pragma unroll
        for (int n = 0; n < 4; n++)
#pragma unroll
            for (int j = 0; j < 4; j++) {
                const int r = crow + m * 16 + j;
                const int c = ccol + n * 16;
                const float v = acc[m][n][j];
                if (EPI == 3) {
                    const float other = __shfl_xor(v, 1);
                    const float res = (v / (1.f + __expf(-v))) * other;  // silu(g1)*g3 on even lanes
                    if (((lane & 1) == 0) && r < mcount)
                        ((bf16*)Cout)[(size_t)(outBase + r) * ldc + (c >> 1)] = f2b(res);
                } else if (r < mcount) {
                    const size_t oi = (size_t)(outBase + r) * ldc + c;
                    if (EPI == 0)      ((bf16*)Cout)[oi] = f2b(v);
                    else if (EPI == 1) ((float*)Cout)[oi] = v;
                    else               ((float*)Cout)[oi] = resid[oi] + v;
                }
            }
}

// ---------------------------------------------------------------------------
// RoPE in-place on q,k sections of qkv [N][3072]; q additionally scaled 1/8.
// ---------------------------------------------------------------------------
__global__ __launch_bounds__(256)
void rope_kernel(bf16* __restrict__ qkv, const float* __restrict__ fc, const float* __restrict__ fs)
{
    const int n = blockIdx.x;
    const int s = n & (S_ - 1);
    bf16* row = qkv + (size_t)n * 3072;
    for (int p = threadIdx.x; p < 1024; p += 256) {
        const int sec = p >> 9;           // 0=q, 1=k
        const int idx = p & 511;
        const int hh = idx >> 5, j = idx & 31;
        const int col = sec * 1024 + hh * 64 + 2 * j;
        const float c = fc[s * 32 + j], si = fs[s * 32 + j];
        const float v0 = b2f(row[col]), v1 = b2f(row[col + 1]);
        float o0 = v0 * c - v1 * si;
        float o1 = v0 * si + v1 * c;
        if (sec == 0) { o0 *= 0.125f; o1 *= 0.125f; }   // fold 1/sqrt(HD) into q
        row[col] = f2b(o0);
        row[col + 1] = f2b(o1);
    }
}

// ---------------------------------------------------------------------------
// Flash attention, non-causal, swapped-operand structure.
// grid (S/128, H=16, B=2), block 256 (4 waves, 32 q-rows/wave). KV tile = 64.
// QK^T computed as mfma(K, Q) -> S^T acc (q = lane&15, kv = (lane>>4)*4+j):
// softmax fully lane-local (2 shfl_xor per reduce), P packs directly into the
// A-operand of PV (no LDS round-trip). V staged row-major in 16-hd chunks and
// read via ds_read_b64_tr_b16 as the PV B-operand (no transpose staging).
// ---------------------------------------------------------------------------
__global__ __launch_bounds__(256)
void attn_kernel(const bf16* __restrict__ qkv, bf16* __restrict__ out)
{
    __shared__ __align__(16) bf16 Ks[64 * 72];          // [kv][64 hd] pad 72
    __shared__ __align__(16) bf16 Vs[4 * 1032 + 8];     // [hd chunk][64 kv][16 hd], chunk stride 1032
    const int tid = threadIdx.x, wave = tid >> 6, lane = tid & 63;
    const int b = blockIdx.z, hh = blockIdx.y;
    const int q0 = blockIdx.x * 128;
    const bf16* base  = qkv + ((size_t)b * S_) * 3072 + (size_t)hh * 64;
    const bf16* kbase = base + 1024;
    const bf16* vbase = base + 2048;
    const int fr = lane & 15, fg = lane >> 4;

    // Q fragments (B-operand): lane holds q = fr, hd = fg*8.. (+32 per s2)
    bf16x8 aq[2][2];
#pragma unroll
    for (int qb = 0; qb < 2; qb++)
#pragma unroll
        for (int s2 = 0; s2 < 2; s2++)
            aq[qb][s2] = ld_bf16x8(base + (size_t)(q0 + wave * 32 + qb * 16 + fr) * 3072 + s2 * 32 + fg * 8);

    f32x4 zero4 = {0.f, 0.f, 0.f, 0.f};
    f32x4 acc_o[2][4];       // [qb][hf]: rows q = fg*4+j, cols hd = hf*16+fr
    float mrow[2], lrow[2];  // per-lane stats for q = fr
#pragma unroll
    for (int qb = 0; qb < 2; qb++) {
#pragma unroll
        for (int hf = 0; hf < 4; hf++) acc_o[qb][hf] = zero4;
        mrow[qb] = -1e30f; lrow[qb] = 0.f;
    }

    const int srow = tid >> 2, sc4 = tid & 3;
    const unsigned vtr0 =
        (unsigned)(uintptr_t)(__attribute__((address_space(3))) void*)&Vs[0] + lane * 8;

    // register-staged K/V prefetch (double-buffered against compute)
    uint4 kg0, kg1, vg0, vg1;
    {
        const bf16* kr = kbase + (size_t)srow * 3072 + sc4 * 16;
        kg0 = *(const uint4*)kr; kg1 = *(const uint4*)(kr + 8);
        const bf16* vr = vbase + (size_t)srow * 3072 + sc4 * 16;
        vg0 = *(const uint4*)vr; vg1 = *(const uint4*)(vr + 8);
    }

    for (int kv0 = 0; kv0 < S_; kv0 += 64) {
        __syncthreads();
        *(uint4*)&Ks[srow * 72 + sc4 * 16]         = kg0;
        *(uint4*)&Ks[srow * 72 + sc4 * 16 + 8]     = kg1;
        *(uint4*)&Vs[sc4 * 1032 + srow * 16]       = vg0;
        *(uint4*)&Vs[sc4 * 1032 + srow * 16 + 8]   = vg1;
        __syncthreads();
        if (kv0 + 64 < S_) {    // prefetch next tile (hides HBM under compute)
            const bf16* kr = kbase + (size_t)(kv0 + 64 + srow) * 3072 + sc4 * 16;
            kg0 = *(const uint4*)kr; kg1 = *(const uint4*)(kr + 8);
            const bf16* vr = vbase + (size_t)(kv0 + 64 + srow) * 3072 + sc4 * 16;
            vg0 = *(const uint4*)vr; vg1 = *(const uint4*)(vr + 8);
        }

        // ---- QK^T (swapped): sc[kt][qb] = K_tile(kt) x Q(qb), S^T layout ----
        f32x4 sc[4][2];
#pragma unroll
        for (int kt = 0; kt < 4; kt++)
#pragma unroll
            for (int qb = 0; qb < 2; qb++) sc[kt][qb] = zero4;
        __builtin_amdgcn_s_setprio(1);
#pragma unroll
        for (int kt = 0; kt < 4; kt++) {
            const bf16x8 k0 = ld_bf16x8(&Ks[(kt * 16 + fr) * 72 + fg * 8]);
            const bf16x8 k1 = ld_bf16x8(&Ks[(kt * 16 + fr) * 72 + 32 + fg * 8]);
#pragma unroll
            for (int qb = 0; qb < 2; qb++) {
                sc[kt][qb] = __builtin_amdgcn_mfma_f32_16x16x32_bf16(k0, aq[qb][0], sc[kt][qb], 0, 0, 0);
                sc[kt][qb] = __builtin_amdgcn_mfma_f32_16x16x32_bf16(k1, aq[qb][1], sc[kt][qb], 0, 0, 0);
            }
        }
        __builtin_amdgcn_s_setprio(0);

        // ---- online softmax, fully in-register (lane owns row q = fr) ----
        bf16x8 pcomb[2][2];   // [qb][tp]: A-operand P fragments (two 16-kv tiles packed)
        float scalv[2];
#pragma unroll
        for (int qb = 0; qb < 2; qb++) {
            float pm = -1e30f;
#pragma unroll
            for (int kt = 0; kt < 4; kt++)
#pragma unroll
                for (int j = 0; j < 4; j++) pm = fmaxf(pm, sc[kt][qb][j]);
            pm = fmaxf(pm, __shfl_xor(pm, 16));
            pm = fmaxf(pm, __shfl_xor(pm, 32));
            const float mnew = fmaxf(mrow[qb], pm);
            const float scal = __expf(mrow[qb] - mnew);
            mrow[qb] = mnew;
            float ps = 0.f;
            union { bf16 h[16]; bf16x8 v8[2]; } pk;
#pragma unroll
            for (int kt = 0; kt < 4; kt++)
#pragma unroll
                for (int j = 0; j < 4; j++) {
                    const float p = __expf(sc[kt][qb][j] - mnew);
                    ps += p;
                    pk.h[kt * 4 + j] = f2b(p);
                }
            pcomb[qb][0] = pk.v8[0];
            pcomb[qb][1] = pk.v8[1];
            ps += __shfl_xor(ps, 16);
            ps += __shfl_xor(ps, 32);
            lrow[qb] = lrow[qb] * scal + ps;
            scalv[qb] = scal;
        }

        // rescale O (its rows are q = fg*4+j -> fetch that q's scal via bpermute)
#pragma unroll
        for (int j = 0; j < 4; j++) {
            const int src = (lane & 48) + fg * 4 + j;
            const float s0 = __shfl(scalv[0], src);
            const float s1 = __shfl(scalv[1], src);
#pragma unroll
            for (int hf = 0; hf < 4; hf++) {
                acc_o[0][hf][j] *= s0;
                acc_o[1][hf][j] *= s1;
            }
        }

        // ---- PV: B-operand via hw transpose-read, two 16-kv tiles per mfma ----
#pragma unroll
        for (int tp = 0; tp < 2; tp++) {
            union { u32x2 d2[2]; bf16x8 v8; } vc[4];
#pragma unroll
            for (int hf = 0; hf < 4; hf++) {
                vc[hf].d2[0] = tr16_read(vtr0 + hf * 2064 + (tp * 2)     * 512);
                vc[hf].d2[1] = tr16_read(vtr0 + hf * 2064 + (tp * 2 + 1) * 512);
            }
            asm volatile("s_waitcnt lgkmcnt(0)" ::: "memory");
            __builtin_amdgcn_sched_barrier(0);   // rule 18: keep MFMAs below the wait
            __builtin_amdgcn_s_setprio(1);
#pragma unroll
            for (int hf = 0; hf < 4; hf++)
#pragma unroll
                for (int qb = 0; qb < 2; qb++)
                    acc_o[qb][hf] = __builtin_amdgcn_mfma_f32_16x16x32_bf16(
                        pcomb[qb][tp], vc[hf].v8, acc_o[qb][hf], 0, 0, 0);
            __builtin_amdgcn_s_setprio(0);
        }
    }

    // ---- epilogue: out rows q = fg*4+j, cols hd = hf*16+fr ----
#pragma unroll
    for (int qb = 0; qb < 2; qb++) {
        const float inv = 1.f / lrow[qb];
#pragma unroll
        for (int j = 0; j < 4; j++) {
            const float ij = __shfl(inv, (lane & 48) + fg * 4 + j);
            const int r = q0 + wave * 32 + qb * 16 + fg * 4 + j;
#pragma unroll
            for (int hf = 0; hf < 4; hf++)
                out[((size_t)(b * S_ + r)) * D_ + hh * 64 + hf * 16 + fr] =
                    f2b(acc_o[qb][hf][j] * ij);
        }
    }
}

// ---------------------------------------------------------------------------
// MoE gating: fp32 scores from pre-norm h (recompute rmsnorm scale), top-2.
// ---------------------------------------------------------------------------
__global__ __launch_bounds__(256)
void gating_kernel(const float* __restrict__ h, const float* __restrict__ gw,
                   const float* __restrict__ wnorm,
                   int* __restrict__ cnt, int* __restrict__ top_idx, float* __restrict__ top_w)
{
    const int wave = threadIdx.x >> 6, lane = threadIdx.x & 63;
    const int n = blockIdx.x * 4 + wave;
    const float* hr = h + (size_t)n * D_;
    float acc[8] = {0.f, 0.f, 0.f, 0.f, 0.f, 0.f, 0.f, 0.f};
    float ss = 0.f;
    for (int d = lane * 4; d < D_; d += 256) {
        const float4 hv = *(const float4*)(hr + d);
        const float4 wv = *(const float4*)(wnorm + d);
        ss += hv.x * hv.x + hv.y * hv.y + hv.z * hv.z + hv.w * hv.w;
        const float x0 = hv.x * wv.x, x1 = hv.y * wv.y, x2 = hv.z * wv.z, x3 = hv.w * wv.w;
#pragma unroll
        for (int e2 = 0; e2 < 8; e2++) {
            const float4 gv = *(const float4*)(gw + e2 * D_ + d);
            acc[e2] += x0 * gv.x + x1 * gv.y + x2 * gv.z + x3 * gv.w;
        }
    }
#pragma unroll
    for (int m = 1; m < 64; m <<= 1) {
        ss += __shfl_xor(ss, m);
#pragma unroll
        for (int e2 = 0; e2 < 8; e2++) acc[e2] += __shfl_xor(acc[e2], m);
    }
    if (lane == 0) {
        const float rstd = rsqrtf(ss * (1.0f / D_) + 1e-6f);
        float s[8];
#pragma unroll
        for (int e2 = 0; e2 < 8; e2++) s[e2] = acc[e2] * rstd;
        int e0 = 0;
#pragma unroll
        for (int e2 = 1; e2 < 8; e2++) if (s[e2] > s[e0]) e0 = e2;
        int e1 = (e0 == 0) ? 1 : 0;
#pragma unroll
        for (int e2 = 0; e2 < 8; e2++) if (e2 != e0 && s[e2] > s[e1]) e1 = e2;
        const float mx = s[e0];
        float Z = 0.f;
        float p[8];
#pragma unroll
        for (int e2 = 0; e2 < 8; e2++) { p[e2] = __expf(s[e2] - mx); Z += p[e2]; }
        const float v0 = p[e0] / Z, v1 = p[e1] / Z;
        const float sm = v0 + v1 + 1e-9f;
        top_idx[n * 2] = e0; top_idx[n * 2 + 1] = e1;
        top_w[n * 2] = v0 / sm; top_w[n * 2 + 1] = v1 / sm;
        atomicAdd(&cnt[e0], 1);
        atomicAdd(&cnt[e1], 1);
    }
}

__global__ __launch_bounds__(64)
void scan_kernel(const int* __restrict__ cnt, int* __restrict__ offs, int* __restrict__ cnt2)
{
    if (threadIdx.x == 0) {
        int o = 0;
        for (int e = 0; e < 8; e++) { offs[e] = o; o += cnt[e]; cnt2[e] = 0; }
        offs[8] = o;
    }
}

__global__ __launch_bounds__(256)
void scatter_kernel(const int* __restrict__ top_idx, int* __restrict__ cnt2,
                    const int* __restrict__ offs, int* __restrict__ token_list,
                    int* __restrict__ tok_pos)
{
    const int n = blockIdx.x * 256 + threadIdx.x;
#pragma unroll
    for (int k = 0; k < 2; k++) {
        const int e = top_idx[n * 2 + k];
        const int pos = offs[e] + atomicAdd(&cnt2[e], 1);
        token_list[pos] = n;
        tok_pos[n * 2 + k] = pos;
    }
}

// out = h + y_shared + w0*eo[pos0] + w1*eo[pos1]
__global__ __launch_bounds__(256)
void combine_kernel(const float* __restrict__ h, const float* __restrict__ y,
                    const bf16* __restrict__ eo, const int* __restrict__ tok_pos,
                    const float* __restrict__ top_w, float* __restrict__ out)
{
    const int idx = blockIdx.x * 256 + threadIdx.x;   // N_*D_/4 total
    const int n = idx >> 8;
    const int c = (idx & 255) * 4;
    const float4 hv = *(const float4*)(h + (size_t)n * D_ + c);
    const float4 yv = *(const float4*)(y + (size_t)n * D_ + c);
    const int p0 = tok_pos[n * 2], p1 = tok_pos[n * 2 + 1];
    const float w0 = top_w[n * 2], w1 = top_w[n * 2 + 1];
    union { uint2 u; bf16 hh[4]; } a0, a1;
    a0.u = *(const uint2*)(eo + (size_t)p0 * D_ + c);
    a1.u = *(const uint2*)(eo + (size_t)p1 * D_ + c);
    float4 r;
    r.x = hv.x + yv.x + w0 * b2f(a0.hh[0]) + w1 * b2f(a1.hh[0]);
    r.y = hv.y + yv.y + w0 * b2f(a0.hh[1]) + w1 * b2f(a1.hh[1]);
    r.z = hv.z + yv.z + w0 * b2f(a0.hh[2]) + w1 * b2f(a1.hh[2]);
    r.w = hv.w + yv.w + w0 * b2f(a0.hh[3]) + w1 * b2f(a1.hh[3]);
    *(float4*)(out + (size_t)n * D_ + c) = r;
}

// ---------------------------------------------------------------------------
extern "C" void kernel_launch(void* const* d_in, const int* in_sizes, int n_in,
                              void* d_out, int out_size, void* d_ws, size_t ws_size,
                              hipStream_t stream)
{
    const float* x   = (const float*)d_in[0];
    const float* fc  = (const float*)d_in[1];
    const float* fs  = (const float*)d_in[2];
    const float* anw = (const float*)d_in[3];
    const float* fnw = (const float*)d_in[4];
    const float* wq  = (const float*)d_in[5];
    const float* wk  = (const float*)d_in[6];
    const float* wv  = (const float*)d_in[7];
    const float* wo  = (const float*)d_in[8];
    const float* gw  = (const float*)d_in[9];
    const float* ew1 = (const float*)d_in[10];
    const float* ew2 = (const float*)d_in[11];
    const float* ew3 = (const float*)d_in[12];
    const float* sw1 = (const float*)d_in[13];
    const float* sw2 = (const float*)d_in[14];
    const float* sw3 = (const float*)d_in[15];

    char* ws = (char*)d_ws;
    bf16*  wqkv_t = (bf16*)(ws + 0);           //  6291456 B  [3072][1024]
    bf16*  wo_t   = (bf16*)(ws + 6291456);     //  2097152 B  [1024][1024]
    bf16*  sw13_t = (bf16*)(ws + 8388608);     //  4194304 B  [2048][1024] interleaved
    bf16*  sw2_t  = (bf16*)(ws + 12582912);    //  2097152 B  [1024][1024]
    bf16*  ew13_t = (bf16*)(ws + 14680064);    // 33554432 B  E x [2048][1024] interleaved
    bf16*  ew2_t  = (bf16*)(ws + 48234496);    // 16777216 B  E x [1024][1024]
    bf16*  xn     = (bf16*)(ws + 65011712);    //  8388608 B  [4096][1024]  (reused as xf)
    bf16*  qkv    = (bf16*)(ws + 73400320);    // 25165824 B  [4096][3072]  (reused as h1 [8192][1024])
    bf16*  attn   = (bf16*)(ws + 98566144);    //  8388608 B  [4096][1024]  (reused as hsh)
    float* hbuf   = (float*)(ws + 106954752);  // 16777216 B  [4096][1024]
    float* ybuf   = (float*)(ws + 123731968);  // 16777216 B  [4096][1024]
    bf16*  eo     = (bf16*)(ws + 140509184);   // 16777216 B  [8192][1024]
    char*  misc   = ws + 157286400;
    int*   cnt        = (int*)(misc + 0);
    int*   cnt2       = (int*)(misc + 32);
    int*   offs       = (int*)(misc + 64);
    int*   top_idx    = (int*)(misc + 128);
    float* top_w      = (float*)(misc + 128 + 32768);
    int*   token_list = (int*)(misc + 128 + 65536);
    int*   tok_pos    = (int*)(misc + 128 + 98304);

    hipMemsetAsync(misc, 0, 128, stream);

    const dim3 tb(256);
    // weight transpose + bf16 convert (all slices are 1024x1024)
    transpose_cvt<<<dim3(32, 32, 1), tb, 0, stream>>>(wq,  wqkv_t,              1024, 1024, 1, 0, 0, 0);
    transpose_cvt<<<dim3(32, 32, 1), tb, 0, stream>>>(wk,  wqkv_t + 1024*1024,  1024, 1024, 1, 0, 0, 0);
    transpose_cvt<<<dim3(32, 32, 1), tb, 0, stream>>>(wv,  wqkv_t + 2048*1024,  1024, 1024, 1, 0, 0, 0);
    transpose_cvt<<<dim3(32, 32, 1), tb, 0, stream>>>(wo,  wo_t,                1024, 1024, 1, 0, 0, 0);
    transpose_cvt<<<dim3(32, 32, 1), tb, 0, stream>>>(sw1, sw13_t,              1024, 1024, 2, 0, 0, 0);
    transpose_cvt<<<dim3(32, 32, 1), tb, 0, stream>>>(sw3, sw13_t,              1024, 1024, 2, 1, 0, 0);
    transpose_cvt<<<dim3(32, 32, 1), tb, 0, stream>>>(sw2, sw2_t,               1024, 1024, 1, 0, 0, 0);
    transpose_cvt<<<dim3(32, 32, 8), tb, 0, stream>>>(ew1, ew13_t,              1024, 1024, 2, 0, 1048576, 2097152);
    transpose_cvt<<<dim3(32, 32, 8), tb, 0, stream>>>(ew3, ew13_t,              1024, 1024, 2, 1, 1048576, 2097152);
    transpose_cvt<<<dim3(32, 32, 8), tb, 0, stream>>>(ew2, ew2_t,               1024, 1024, 1, 0, 1048576, 1048576);

    // attention branch
    rmsnorm_kernel<<<N_, tb, 0, stream>>>(x, anw, xn);
    gemm_bt<0, 0><<<dim3(24, 32, 1), tb, 0, stream>>>(xn, wqkv_t, qkv, nullptr,
        N_, 1024, 1024, 1024, 3072, 0, nullptr, nullptr, nullptr);
    rope_kernel<<<N_, tb, 0, stream>>>(qkv, fc, fs);
    attn_kernel<<<dim3(16, 16, 2), tb, 0, stream>>>(qkv, attn);
    gemm_bt<2, 0><<<dim3(8, 32, 1), tb, 0, stream>>>(attn, wo_t, hbuf, x,
        N_, 1024, 1024, 1024, 1024, 0, nullptr, nullptr, nullptr);

    // FFN branch
    rmsnorm_kernel<<<N_, tb, 0, stream>>>(hbuf, fnw, xn);   // xn = xf now
    gating_kernel<<<N_ / 4, tb, 0, stream>>>(hbuf, gw, fnw, cnt, top_idx, top_w);
    scan_kernel<<<1, 64, 0, stream>>>(cnt, offs, cnt2);
    scatter_kernel<<<N_ / 256, tb, 0, stream>>>(top_idx, cnt2, offs, token_list, tok_pos);

    // shared expert: hsh = silu(xf@sw1)*(xf@sw3); y = hsh@sw2
    gemm_bt<3, 0><<<dim3(16, 32, 1), tb, 0, stream>>>(xn, sw13_t, attn, nullptr,
        N_, 1024, 1024, 1024, 1024, 0, nullptr, nullptr, nullptr);      // attn = hsh now
    gemm_bt<1, 0><<<dim3(8, 32, 1), tb, 0, stream>>>(attn, sw2_t, ybuf, nullptr,
        N_, 1024, 1024, 1024, 1024, 0, nullptr, nullptr, nullptr);

    // routed experts (top-2): h1 = silu(xg@ew1)*(xg@ew3); eo = h1@ew2
    gemm_bt<3, 1><<<dim3(16, 32, 8), tb, 0, stream>>>(xn, ew13_t, qkv, nullptr,
        0, 1024, 1024, 1024, 1024, 2097152, token_list, offs, cnt);     // qkv = h1 now
    gemm_bt<0, 2><<<dim3(8, 32, 8), tb, 0, stream>>>((const bf16*)qkv, ew2_t, eo, nullptr,
        0, 1024, 1024, 1024, 1024, 1048576, nullptr, offs, cnt);

    combine_kernel<<<4096, tb, 0, stream>>>(hbuf, ybuf, eo, tok_pos, top_w, (float*)d_out);
}

// Round 3
// 418.325 us; speedup vs baseline: 1.5050x; 1.3302x over previous
//
#include <hip/hip_runtime.h>
#include <hip/hip_bf16.h>
#include <stdint.h>

// Transformer block for MI355X (gfx950).
// B=2 S=2048 D=1024 H=16 HD=64 E=8 K=2 HM=HS=1024, fp32 in/out, bf16 MFMA compute.

typedef __hip_bfloat16 bf16;
typedef __attribute__((ext_vector_type(8))) __bf16 bf16x8;
typedef __attribute__((ext_vector_type(4))) float f32x4;
typedef __attribute__((ext_vector_type(2))) unsigned int u32x2;

#define S_  2048
#define D_  1024
#define N_  4096      // B*S
#define HM_ 1024
#define HS_ 1024

__device__ __forceinline__ float b2f(bf16 h) { return __bfloat162float(h); }
__device__ __forceinline__ bf16  f2b(float f) { return __float2bfloat16(f); }

__device__ __forceinline__ bf16x8 ld_bf16x8(const bf16* p) {
    union { uint4 u; bf16x8 v; } x;
    x.u = *(const uint4*)p;
    return x.v;
}

__device__ __forceinline__ void gload_lds16(const void* gsrc, void* ldst) {
    __builtin_amdgcn_global_load_lds(
        (__attribute__((address_space(1))) void*)const_cast<void*>(gsrc),
        (__attribute__((address_space(3))) void*)ldst, 16, 0, 0);
}

// gfx950 LDS transpose read: lane l gets column (l&15) of the 4x16 bf16 tile
// supplied by its 16-lane group's 128B window (per-lane addr = base + 8*lane).
__device__ __forceinline__ u32x2 tr16_read(unsigned lds_off) {
    u32x2 d;
    asm volatile("ds_read_b64_tr_b16 %0, %1" : "=v"(d) : "v"(lds_off));
    return d;
}

// ---------------------------------------------------------------------------
// fp32 -> bf16 transpose-convert: out[(c*rowmul+rowoff)*ld_out + r] = in[r*ld_in + c]
// ---------------------------------------------------------------------------
__global__ __launch_bounds__(256)
void transpose_cvt(const float* __restrict__ in, bf16* __restrict__ out,
                   int ld_in, int ld_out, int rowmul, int rowoff,
                   long in_bstride, long out_bstride)
{
    __shared__ float t[32][33];
    const int e = blockIdx.z;
    in  += (size_t)e * in_bstride;
    out += (size_t)e * out_bstride;
    const int c0 = blockIdx.x * 32, r0 = blockIdx.y * 32;
    const int tx = threadIdx.x & 31, ty = threadIdx.x >> 5;   // ty 0..7
#pragma unroll
    for (int i = 0; i < 32; i += 8)
        t[ty + i][tx] = in[(size_t)(r0 + ty + i) * ld_in + c0 + tx];
    __syncthreads();
#pragma unroll
    for (int i = 0; i < 32; i += 8)
        out[(size_t)((c0 + ty + i) * rowmul + rowoff) * ld_out + r0 + tx] = f2b(t[tx][ty + i]);
}

// ---------------------------------------------------------------------------
// RMSNorm: fp32 in -> bf16 out.  grid N_, block 256
// ---------------------------------------------------------------------------
__global__ __launch_bounds__(256)
void rmsnorm_kernel(const float* __restrict__ x, const float* __restrict__ w,
                    bf16* __restrict__ out)
{
    const int n = blockIdx.x;
    const int tid = threadIdx.x;
    const float4 v = *(const float4*)(x + (size_t)n * D_ + tid * 4);
    float ss = v.x * v.x + v.y * v.y + v.z * v.z + v.w * v.w;
#pragma unroll
    for (int m = 1; m < 64; m <<= 1) ss += __shfl_xor(ss, m);
    __shared__ float red[4];
    if ((tid & 63) == 0) red[tid >> 6] = ss;
    __syncthreads();
    const float tot = red[0] + red[1] + red[2] + red[3];
    const float rstd = rsqrtf(tot * (1.0f / D_) + 1e-6f);
    const float4 wv = *(const float4*)(w + tid * 4);
    union { bf16 h[4]; uint2 u; } pk;
    pk.h[0] = f2b(v.x * rstd * wv.x);
    pk.h[1] = f2b(v.y * rstd * wv.y);
    pk.h[2] = f2b(v.z * rstd * wv.z);
    pk.h[3] = f2b(v.w * rstd * wv.w);
    *(uint2*)(out + (size_t)n * D_ + tid * 4) = pk.u;
}

// ---------------------------------------------------------------------------
// GEMM: C[M][N] = A[M][K] * Bt[N][K]^T  (A,Bt bf16 row-major; acc fp32)
// 128x128 tile, BK=32, 256 threads (4 waves, 2x2), mfma 16x16x32 bf16.
// EPI: 0 = store bf16, 1 = store fp32, 2 = fp32 resid add, 3 = swiglu pair -> bf16
// MODE: 0 = plain, 1 = grouped+gathered A rows (token_list), 2 = grouped contiguous
// ---------------------------------------------------------------------------
template<int EPI, int MODE>
__global__ __launch_bounds__(256)
void gemm_bt(const bf16* __restrict__ A, const bf16* __restrict__ Bt,
             void* __restrict__ Cout, const float* __restrict__ resid,
             int M, int Kdim, int lda, int ldb, int ldc, long bstride,
             const int* __restrict__ tlist, const int* __restrict__ offs)
{
    __shared__ bf16 As[128 * 32];
    __shared__ bf16 Bs[128 * 32];
    const int tid = threadIdx.x;
    const int wave = tid >> 6, lane = tid & 63;

    int mcount = M, outBase = 0;
    const bf16* Bp = Bt;
    if (MODE != 0) {
        const int e = blockIdx.z;
        outBase = offs[e];
        mcount = offs[e + 1] - outBase;
        Bp = Bt + (size_t)e * bstride;
    }
    const int m0 = blockIdx.y * 128;
    if (m0 >= mcount) return;
    const int n0 = blockIdx.x * 128;

    const int srow = tid >> 2;
    const int scol = (tid & 3) * 8;
    const bf16* aptr[2];
    const bf16* bptr[2];
#pragma unroll
    for (int i = 0; i < 2; i++) {
        int r = m0 + i * 64 + srow;
        if (r >= mcount) r = mcount - 1;
        long arow;
        if (MODE == 1)      arow = tlist[outBase + r];
        else if (MODE == 2) arow = (long)outBase + r;
        else                arow = r;
        aptr[i] = A + (size_t)arow * lda + scol;
        bptr[i] = Bp + (size_t)(n0 + i * 64 + srow) * ldb + scol;
    }

    f32x4 zero4 = {0.f, 0.f, 0.f, 0.f};
    f32x4 acc[4][4];
#pragma unroll
    for (int m = 0; m < 4; m++)
#pragma unroll
        for (int n = 0; n < 4; n++) acc[m][n] = zero4;

    const int wm = (wave >> 1) * 64, wn = (wave & 1) * 64;
    const int fr = lane & 15, fk = (lane >> 4) * 8;
    const int aoff = (wm + fr) * 32 + fk;
    const int boff = (wn + fr) * 32 + fk;

    for (int kt = 0; kt < Kdim; kt += 32) {
        __syncthreads();
#pragma unroll
        for (int i = 0; i < 2; i++) {
            gload_lds16(aptr[i] + kt, (char*)As + i * 4096 + wave * 1024);
            gload_lds16(bptr[i] + kt, (char*)Bs + i * 4096 + wave * 1024);
        }
        __syncthreads();
        bf16x8 af[4], bfr[4];
#pragma unroll
        for (int m = 0; m < 4; m++) af[m] = ld_bf16x8(&As[aoff + m * 512]);
#pragma unroll
        for (int n = 0; n < 4; n++) bfr[n] = ld_bf16x8(&Bs[boff + n * 512]);
#pragma unroll
        for (int m = 0; m < 4; m++)
#pragma unroll
            for (int n = 0; n < 4; n++)
                acc[m][n] = __builtin_amdgcn_mfma_f32_16x16x32_bf16(af[m], bfr[n], acc[m][n], 0, 0, 0);
    }

    const int crow = m0 + wm + (lane >> 4) * 4;
    const int ccol = n0 + wn + fr;
#pragma unroll
    for (int m = 0; m < 4; m++)
#pragma unroll
        for (int n = 0; n < 4; n++)
#pragma unroll
            for (int j = 0; j < 4; j++) {
                const int r = crow + m * 16 + j;
                const int c = ccol + n * 16;
                const float v = acc[m][n][j];
                if (EPI == 3) {
                    const float other = __shfl_xor(v, 1);
                    const float res = (v / (1.f + __expf(-v))) * other;  // silu(g1)*g3 on even lanes
                    if (((lane & 1) == 0) && r < mcount)
                        ((bf16*)Cout)[(size_t)(outBase + r) * ldc + (c >> 1)] = f2b(res);
                } else if (r < mcount) {
                    const size_t oi = (size_t)(outBase + r) * ldc + c;
                    if (EPI == 0)      ((bf16*)Cout)[oi] = f2b(v);
                    else if (EPI == 1) ((float*)Cout)[oi] = v;
                    else               ((float*)Cout)[oi] = resid[oi] + v;
                }
            }
}

// ---------------------------------------------------------------------------
// RoPE in-place on q,k sections of qkv [N][3072]; q additionally scaled 1/8.
// ---------------------------------------------------------------------------
__global__ __launch_bounds__(256)
void rope_kernel(bf16* __restrict__ qkv, const float* __restrict__ fc, const float* __restrict__ fs)
{
    const int n = blockIdx.x;
    const int s = n & (S_ - 1);
    bf16* row = qkv + (size_t)n * 3072;
    for (int p = threadIdx.x; p < 1024; p += 256) {
        const int sec = p >> 9;           // 0=q, 1=k
        const int idx = p & 511;
        const int hh = idx >> 5, j = idx & 31;
        const int col = sec * 1024 + hh * 64 + 2 * j;
        const float c = fc[s * 32 + j], si = fs[s * 32 + j];
        const float v0 = b2f(row[col]), v1 = b2f(row[col + 1]);
        float o0 = v0 * c - v1 * si;
        float o1 = v0 * si + v1 * c;
        if (sec == 0) { o0 *= 0.125f; o1 *= 0.125f; }   // fold 1/sqrt(HD) into q
        row[col] = f2b(o0);
        row[col + 1] = f2b(o1);
    }
}

// ---------------------------------------------------------------------------
// Flash attention, non-causal, swapped-operand structure.
// grid (S/128, H=16, B=2), block 256 (4 waves, 32 q-rows/wave). KV tile = 64.
// ---------------------------------------------------------------------------
__global__ __launch_bounds__(256)
void attn_kernel(const bf16* __restrict__ qkv, bf16* __restrict__ out)
{
    __shared__ __align__(16) bf16 Ks[64 * 72];          // [kv][64 hd] pad 72
    __shared__ __align__(16) bf16 Vs[4 * 1032 + 8];     // [hd chunk][64 kv][16 hd], chunk stride 1032
    const int tid = threadIdx.x, wave = tid >> 6, lane = tid & 63;
    const int b = blockIdx.z, hh = blockIdx.y;
    const int q0 = blockIdx.x * 128;
    const bf16* base  = qkv + ((size_t)b * S_) * 3072 + (size_t)hh * 64;
    const bf16* kbase = base + 1024;
    const bf16* vbase = base + 2048;
    const int fr = lane & 15, fg = lane >> 4;

    // Q fragments (B-operand): lane holds q = fr, hd = fg*8.. (+32 per s2)
    bf16x8 aq[2][2];
#pragma unroll
    for (int qb = 0; qb < 2; qb++)
#pragma unroll
        for (int s2 = 0; s2 < 2; s2++)
            aq[qb][s2] = ld_bf16x8(base + (size_t)(q0 + wave * 32 + qb * 16 + fr) * 3072 + s2 * 32 + fg * 8);

    f32x4 zero4 = {0.f, 0.f, 0.f, 0.f};
    f32x4 acc_o[2][4];       // [qb][hf]: rows q = fg*4+j, cols hd = hf*16+fr
    float mrow[2], lrow[2];  // per-lane stats for q = fr
#pragma unroll
    for (int qb = 0; qb < 2; qb++) {
#pragma unroll
        for (int hf = 0; hf < 4; hf++) acc_o[qb][hf] = zero4;
        mrow[qb] = -1e30f; lrow[qb] = 0.f;
    }

    const int srow = tid >> 2, sc4 = tid & 3;
    const unsigned vtr0 =
        (unsigned)(uintptr_t)(__attribute__((address_space(3))) void*)&Vs[0] + lane * 8;

    // register-staged K/V prefetch (double-buffered against compute)
    uint4 kg0, kg1, vg0, vg1;
    {
        const bf16* kr = kbase + (size_t)srow * 3072 + sc4 * 16;
        kg0 = *(const uint4*)kr; kg1 = *(const uint4*)(kr + 8);
        const bf16* vr = vbase + (size_t)srow * 3072 + sc4 * 16;
        vg0 = *(const uint4*)vr; vg1 = *(const uint4*)(vr + 8);
    }

    for (int kv0 = 0; kv0 < S_; kv0 += 64) {
        __syncthreads();
        *(uint4*)&Ks[srow * 72 + sc4 * 16]         = kg0;
        *(uint4*)&Ks[srow * 72 + sc4 * 16 + 8]     = kg1;
        *(uint4*)&Vs[sc4 * 1032 + srow * 16]       = vg0;
        *(uint4*)&Vs[sc4 * 1032 + srow * 16 + 8]   = vg1;
        __syncthreads();
        if (kv0 + 64 < S_) {    // prefetch next tile (hides HBM under compute)
            const bf16* kr = kbase + (size_t)(kv0 + 64 + srow) * 3072 + sc4 * 16;
            kg0 = *(const uint4*)kr; kg1 = *(const uint4*)(kr + 8);
            const bf16* vr = vbase + (size_t)(kv0 + 64 + srow) * 3072 + sc4 * 16;
            vg0 = *(const uint4*)vr; vg1 = *(const uint4*)(vr + 8);
        }

        // ---- QK^T (swapped): sc[kt][qb] = K_tile(kt) x Q(qb), S^T layout ----
        f32x4 sc[4][2];
#pragma unroll
        for (int kt = 0; kt < 4; kt++)
#pragma unroll
            for (int qb = 0; qb < 2; qb++) sc[kt][qb] = zero4;
        __builtin_amdgcn_s_setprio(1);
#pragma unroll
        for (int kt = 0; kt < 4; kt++) {
            const bf16x8 k0 = ld_bf16x8(&Ks[(kt * 16 + fr) * 72 + fg * 8]);
            const bf16x8 k1 = ld_bf16x8(&Ks[(kt * 16 + fr) * 72 + 32 + fg * 8]);
#pragma unroll
            for (int qb = 0; qb < 2; qb++) {
                sc[kt][qb] = __builtin_amdgcn_mfma_f32_16x16x32_bf16(k0, aq[qb][0], sc[kt][qb], 0, 0, 0);
                sc[kt][qb] = __builtin_amdgcn_mfma_f32_16x16x32_bf16(k1, aq[qb][1], sc[kt][qb], 0, 0, 0);
            }
        }
        __builtin_amdgcn_s_setprio(0);

        // ---- online softmax, fully in-register (lane owns row q = fr) ----
        bf16x8 pcomb[2][2];   // [qb][tp]: A-operand P fragments (two 16-kv tiles packed)
        float scalv[2];
#pragma unroll
        for (int qb = 0; qb < 2; qb++) {
            float pm = -1e30f;
#pragma unroll
            for (int kt = 0; kt < 4; kt++)
#pragma unroll
                for (int j = 0; j < 4; j++) pm = fmaxf(pm, sc[kt][qb][j]);
            pm = fmaxf(pm, __shfl_xor(pm, 16));
            pm = fmaxf(pm, __shfl_xor(pm, 32));
            const float mnew = fmaxf(mrow[qb], pm);
            const float scal = __expf(mrow[qb] - mnew);
            mrow[qb] = mnew;
            float ps = 0.f;
            union { bf16 h[16]; bf16x8 v8[2]; } pk;
#pragma unroll
            for (int kt = 0; kt < 4; kt++)
#pragma unroll
                for (int j = 0; j < 4; j++) {
                    const float p = __expf(sc[kt][qb][j] - mnew);
                    ps += p;
                    pk.h[kt * 4 + j] = f2b(p);
                }
            pcomb[qb][0] = pk.v8[0];
            pcomb[qb][1] = pk.v8[1];
            ps += __shfl_xor(ps, 16);
            ps += __shfl_xor(ps, 32);
            lrow[qb] = lrow[qb] * scal + ps;
            scalv[qb] = scal;
        }

        // rescale O (its rows are q = fg*4+j -> fetch that q's scal)
#pragma unroll
        for (int j = 0; j < 4; j++) {
            const int src = (lane & 48) + fg * 4 + j;
            const float s0 = __shfl(scalv[0], src);
            const float s1 = __shfl(scalv[1], src);
#pragma unroll
            for (int hf = 0; hf < 4; hf++) {
                acc_o[0][hf][j] *= s0;
                acc_o[1][hf][j] *= s1;
            }
        }

        // ---- PV: B-operand via hw transpose-read, two 16-kv tiles per mfma ----
#pragma unroll
        for (int tp = 0; tp < 2; tp++) {
            union { u32x2 d2[2]; bf16x8 v8; } vc[4];
#pragma unroll
            for (int hf = 0; hf < 4; hf++) {
                vc[hf].d2[0] = tr16_read(vtr0 + hf * 2064 + (tp * 2)     * 512);
                vc[hf].d2[1] = tr16_read(vtr0 + hf * 2064 + (tp * 2 + 1) * 512);
            }
            asm volatile("s_waitcnt lgkmcnt(0)" ::: "memory");
            __builtin_amdgcn_sched_barrier(0);   // rule 18: keep MFMAs below the wait
            __builtin_amdgcn_s_setprio(1);
#pragma unroll
            for (int hf = 0; hf < 4; hf++)
#pragma unroll
                for (int qb = 0; qb < 2; qb++)
                    acc_o[qb][hf] = __builtin_amdgcn_mfma_f32_16x16x32_bf16(
                        pcomb[qb][tp], vc[hf].v8, acc_o[qb][hf], 0, 0, 0);
            __builtin_amdgcn_s_setprio(0);
        }
    }

    // ---- epilogue: out rows q = fg*4+j, cols hd = hf*16+fr ----
#pragma unroll
    for (int qb = 0; qb < 2; qb++) {
        const float inv = 1.f / lrow[qb];
#pragma unroll
        for (int j = 0; j < 4; j++) {
            const float ij = __shfl(inv, (lane & 48) + fg * 4 + j);
            const int r = q0 + wave * 32 + qb * 16 + fg * 4 + j;
#pragma unroll
            for (int hf = 0; hf < 4; hf++)
                out[((size_t)(b * S_ + r)) * D_ + hh * 64 + hf * 16 + fr] =
                    f2b(acc_o[qb][hf][j] * ij);
        }
    }
}

// ---------------------------------------------------------------------------
// MoE gating: fp32 scores from pre-norm h (recompute rmsnorm scale), top-2.
// NO global atomics (they serialized cross-XCD: 8192 RMWs on one line = 103us).
// ---------------------------------------------------------------------------
__global__ __launch_bounds__(256)
void gating_kernel(const float* __restrict__ h, const float* __restrict__ gw,
                   const float* __restrict__ wnorm,
                   int* __restrict__ top_idx, float* __restrict__ top_w)
{
    const int wave = threadIdx.x >> 6, lane = threadIdx.x & 63;
    const int n = blockIdx.x * 4 + wave;
    const float* hr = h + (size_t)n * D_;
    float acc[8] = {0.f, 0.f, 0.f, 0.f, 0.f, 0.f, 0.f, 0.f};
    float ss = 0.f;
    for (int d = lane * 4; d < D_; d += 256) {
        const float4 hv = *(const float4*)(hr + d);
        const float4 wv = *(const float4*)(wnorm + d);
        ss += hv.x * hv.x + hv.y * hv.y + hv.z * hv.z + hv.w * hv.w;
        const float x0 = hv.x * wv.x, x1 = hv.y * wv.y, x2 = hv.z * wv.z, x3 = hv.w * wv.w;
#pragma unroll
        for (int e2 = 0; e2 < 8; e2++) {
            const float4 gv = *(const float4*)(gw + e2 * D_ + d);
            acc[e2] += x0 * gv.x + x1 * gv.y + x2 * gv.z + x3 * gv.w;
        }
    }
#pragma unroll
    for (int m = 1; m < 64; m <<= 1) {
        ss += __shfl_xor(ss, m);
#pragma unroll
        for (int e2 = 0; e2 < 8; e2++) acc[e2] += __shfl_xor(acc[e2], m);
    }
    if (lane == 0) {
        const float rstd = rsqrtf(ss * (1.0f / D_) + 1e-6f);
        float s[8];
#pragma unroll
        for (int e2 = 0; e2 < 8; e2++) s[e2] = acc[e2] * rstd;
        int e0 = 0;
#pragma unroll
        for (int e2 = 1; e2 < 8; e2++) if (s[e2] > s[e0]) e0 = e2;
        int e1 = (e0 == 0) ? 1 : 0;
#pragma unroll
        for (int e2 = 0; e2 < 8; e2++) if (e2 != e0 && s[e2] > s[e1]) e1 = e2;
        const float mx = s[e0];
        float Z = 0.f;
        float p[8];
#pragma unroll
        for (int e2 = 0; e2 < 8; e2++) { p[e2] = __expf(s[e2] - mx); Z += p[e2]; }
        const float v0 = p[e0] / Z, v1 = p[e1] / Z;
        const float sm = v0 + v1 + 1e-9f;
        top_idx[n * 2] = e0; top_idx[n * 2 + 1] = e1;
        top_w[n * 2] = v0 / sm; top_w[n * 2 + 1] = v1 / sm;
    }
}

// ---------------------------------------------------------------------------
// Routing: single block, LDS atomics only. histogram -> offsets -> scatter.
// 8192 (token,slot) entries; 1024 threads x 8 entries each.
// ---------------------------------------------------------------------------
__global__ __launch_bounds__(1024)
void route_kernel(const int* __restrict__ top_idx, int* __restrict__ offs,
                  int* __restrict__ token_list, int* __restrict__ tok_pos)
{
    __shared__ int hist[8];
    __shared__ int base[8];
    const int tid = threadIdx.x;
    if (tid < 8) hist[tid] = 0;
    __syncthreads();
    int4 e4a = *(const int4*)(top_idx + tid * 8);
    int4 e4b = *(const int4*)(top_idx + tid * 8 + 4);
    int myidx[8] = {e4a.x, e4a.y, e4a.z, e4a.w, e4b.x, e4b.y, e4b.z, e4b.w};
#pragma unroll
    for (int i = 0; i < 8; i++) atomicAdd(&hist[myidx[i]], 1);
    __syncthreads();
    if (tid == 0) {
        int o = 0;
#pragma unroll
        for (int e = 0; e < 8; e++) { base[e] = o; offs[e] = o; o += hist[e]; }
        offs[8] = o;
    }
    __syncthreads();
    if (tid < 8) hist[tid] = 0;
    __syncthreads();
#pragma unroll
    for (int i = 0; i < 8; i++) {
        const int entry = tid * 8 + i;
        const int e = myidx[i];
        const int pos = base[e] + atomicAdd(&hist[e], 1);
        token_list[pos] = entry >> 1;
        tok_pos[entry] = pos;
    }
}

// out = h + y_shared + w0*eo[pos0] + w1*eo[pos1]
__global__ __launch_bounds__(256)
void combine_kernel(const float* __restrict__ h, const float* __restrict__ y,
                    const bf16* __restrict__ eo, const int* __restrict__ tok_pos,
                    const float* __restrict__ top_w, float* __restrict__ out)
{
    const int idx = blockIdx.x * 256 + threadIdx.x;   // N_*D_/4 total
    const int n = idx >> 8;
    const int c = (idx & 255) * 4;
    const float4 hv = *(const float4*)(h + (size_t)n * D_ + c);
    const float4 yv = *(const float4*)(y + (size_t)n * D_ + c);
    const int p0 = tok_pos[n * 2], p1 = tok_pos[n * 2 + 1];
    const float w0 = top_w[n * 2], w1 = top_w[n * 2 + 1];
    union { uint2 u; bf16 hh[4]; } a0, a1;
    a0.u = *(const uint2*)(eo + (size_t)p0 * D_ + c);
    a1.u = *(const uint2*)(eo + (size_t)p1 * D_ + c);
    float4 r;
    r.x = hv.x + yv.x + w0 * b2f(a0.hh[0]) + w1 * b2f(a1.hh[0]);
    r.y = hv.y + yv.y + w0 * b2f(a0.hh[1]) + w1 * b2f(a1.hh[1]);
    r.z = hv.z + yv.z + w0 * b2f(a0.hh[2]) + w1 * b2f(a1.hh[2]);
    r.w = hv.w + yv.w + w0 * b2f(a0.hh[3]) + w1 * b2f(a1.hh[3]);
    *(float4*)(out + (size_t)n * D_ + c) = r;
}

// ---------------------------------------------------------------------------
extern "C" void kernel_launch(void* const* d_in, const int* in_sizes, int n_in,
                              void* d_out, int out_size, void* d_ws, size_t ws_size,
                              hipStream_t stream)
{
    const float* x   = (const float*)d_in[0];
    const float* fc  = (const float*)d_in[1];
    const float* fs  = (const float*)d_in[2];
    const float* anw = (const float*)d_in[3];
    const float* fnw = (const float*)d_in[4];
    const float* wq  = (const float*)d_in[5];
    const float* wk  = (const float*)d_in[6];
    const float* wv  = (const float*)d_in[7];
    const float* wo  = (const float*)d_in[8];
    const float* gw  = (const float*)d_in[9];
    const float* ew1 = (const float*)d_in[10];
    const float* ew2 = (const float*)d_in[11];
    const float* ew3 = (const float*)d_in[12];
    const float* sw1 = (const float*)d_in[13];
    const float* sw2 = (const float*)d_in[14];
    const float* sw3 = (const float*)d_in[15];

    char* ws = (char*)d_ws;
    bf16*  wqkv_t = (bf16*)(ws + 0);           //  6291456 B  [3072][1024]
    bf16*  wo_t   = (bf16*)(ws + 6291456);     //  2097152 B  [1024][1024]
    bf16*  sw13_t = (bf16*)(ws + 8388608);     //  4194304 B  [2048][1024] interleaved
    bf16*  sw2_t  = (bf16*)(ws + 12582912);    //  2097152 B  [1024][1024]
    bf16*  ew13_t = (bf16*)(ws + 14680064);    // 33554432 B  E x [2048][1024] interleaved
    bf16*  ew2_t  = (bf16*)(ws + 48234496);    // 16777216 B  E x [1024][1024]
    bf16*  xn     = (bf16*)(ws + 65011712);    //  8388608 B  [4096][1024]  (reused as xf)
    bf16*  qkv    = (bf16*)(ws + 73400320);    // 25165824 B  [4096][3072]  (reused as h1 [8192][1024])
    bf16*  attn   = (bf16*)(ws + 98566144);    //  8388608 B  [4096][1024]  (reused as hsh)
    float* hbuf   = (float*)(ws + 106954752);  // 16777216 B  [4096][1024]
    float* ybuf   = (float*)(ws + 123731968);  // 16777216 B  [4096][1024]
    bf16*  eo     = (bf16*)(ws + 140509184);   // 16777216 B  [8192][1024]
    char*  misc   = ws + 157286400;
    int*   offs       = (int*)(misc + 64);
    int*   top_idx    = (int*)(misc + 128);
    float* top_w      = (float*)(misc + 128 + 32768);
    int*   token_list = (int*)(misc + 128 + 65536);
    int*   tok_pos    = (int*)(misc + 128 + 98304);

    const dim3 tb(256);
    // weight transpose + bf16 convert (all slices are 1024x1024)
    transpose_cvt<<<dim3(32, 32, 1), tb, 0, stream>>>(wq,  wqkv_t,              1024, 1024, 1, 0, 0, 0);
    transpose_cvt<<<dim3(32, 32, 1), tb, 0, stream>>>(wk,  wqkv_t + 1024*1024,  1024, 1024, 1, 0, 0, 0);
    transpose_cvt<<<dim3(32, 32, 1), tb, 0, stream>>>(wv,  wqkv_t + 2048*1024,  1024, 1024, 1, 0, 0, 0);
    transpose_cvt<<<dim3(32, 32, 1), tb, 0, stream>>>(wo,  wo_t,                1024, 1024, 1, 0, 0, 0);
    transpose_cvt<<<dim3(32, 32, 1), tb, 0, stream>>>(sw1, sw13_t,              1024, 1024, 2, 0, 0, 0);
    transpose_cvt<<<dim3(32, 32, 1), tb, 0, stream>>>(sw3, sw13_t,              1024, 1024, 2, 1, 0, 0);
    transpose_cvt<<<dim3(32, 32, 1), tb, 0, stream>>>(sw2, sw2_t,               1024, 1024, 1, 0, 0, 0);
    transpose_cvt<<<dim3(32, 32, 8), tb, 0, stream>>>(ew1, ew13_t,              1024, 1024, 2, 0, 1048576, 2097152);
    transpose_cvt<<<dim3(32, 32, 8), tb, 0, stream>>>(ew3, ew13_t,              1024, 1024, 2, 1, 1048576, 2097152);
    transpose_cvt<<<dim3(32, 32, 8), tb, 0, stream>>>(ew2, ew2_t,               1024, 1024, 1, 0, 1048576, 1048576);

    // attention branch
    rmsnorm_kernel<<<N_, tb, 0, stream>>>(x, anw, xn);
    gemm_bt<0, 0><<<dim3(24, 32, 1), tb, 0, stream>>>(xn, wqkv_t, qkv, nullptr,
        N_, 1024, 1024, 1024, 3072, 0, nullptr, nullptr);
    rope_kernel<<<N_, tb, 0, stream>>>(qkv, fc, fs);
    attn_kernel<<<dim3(16, 16, 2), tb, 0, stream>>>(qkv, attn);
    gemm_bt<2, 0><<<dim3(8, 32, 1), tb, 0, stream>>>(attn, wo_t, hbuf, x,
        N_, 1024, 1024, 1024, 1024, 0, nullptr, nullptr);

    // FFN branch
    rmsnorm_kernel<<<N_, tb, 0, stream>>>(hbuf, fnw, xn);   // xn = xf now
    gating_kernel<<<N_ / 4, tb, 0, stream>>>(hbuf, gw, fnw, top_idx, top_w);
    route_kernel<<<1, 1024, 0, stream>>>(top_idx, offs, token_list, tok_pos);

    // shared expert: hsh = silu(xf@sw1)*(xf@sw3); y = hsh@sw2
    gemm_bt<3, 0><<<dim3(16, 32, 1), tb, 0, stream>>>(xn, sw13_t, attn, nullptr,
        N_, 1024, 1024, 1024, 1024, 0, nullptr, nullptr);      // attn = hsh now
    gemm_bt<1, 0><<<dim3(8, 32, 1), tb, 0, stream>>>(attn, sw2_t, ybuf, nullptr,
        N_, 1024, 1024, 1024, 1024, 0, nullptr, nullptr);

    // routed experts (top-2): h1 = silu(xg@ew1)*(xg@ew3); eo = h1@ew2
    gemm_bt<3, 1><<<dim3(16, 32, 8), tb, 0, stream>>>(xn, ew13_t, qkv, nullptr,
        0, 1024, 1024, 1024, 1024, 2097152, token_list, offs);     // qkv = h1 now
    gemm_bt<0, 2><<<dim3(8, 32, 8), tb, 0, stream>>>((const bf16*)qkv, ew2_t, eo, nullptr,
        0, 1024, 1024, 1024, 1024, 1048576, nullptr, offs);

    combine_kernel<<<4096, tb, 0, stream>>>(hbuf, ybuf, eo, tok_pos, top_w, (float*)d_out);
}